// Round 6
// baseline (437.489 us; speedup 1.0000x reference)
//
#include <hip/hip_runtime.h>

// Whisper-style self-attention, B=8 T=1024 D=1280 H=20 DH=64, fp32 I/O.
#define BB 8
#define TT 1024
#define DD 1280
#define HH 20
#define DHH 64
#define MM (BB*TT)      // 8192 rows
#define NT 20           // K-tiles of BK=64

typedef _Float16 f16;
typedef f16 f16x8 __attribute__((ext_vector_type(8)));
typedef f16 f16x4 __attribute__((ext_vector_type(4)));
typedef float f32x4 __attribute__((ext_vector_type(4)));

// async global->LDS, 16B per lane. LDS dest = wave-uniform base + lane*16.
__device__ __forceinline__ void async16(const f16* g, f16* l) {
  __builtin_amdgcn_global_load_lds((const __attribute__((address_space(1))) void*)g,
                                   (__attribute__((address_space(3))) void*)l, 16, 0, 0);
}

// ---------------------------------------------------------------------------
// prep: fused {Wq,Wk,Wv,Wo transpose+cast} and {x fp32->f16}.
// ---------------------------------------------------------------------------
__global__ __launch_bounds__(256) void prep(const float* __restrict__ Wq,
                                            const float* __restrict__ Wk,
                                            const float* __restrict__ Wv,
                                            const float* __restrict__ Wo,
                                            const float* __restrict__ x,
                                            f16* __restrict__ wqkv_t,
                                            f16* __restrict__ wo_t,
                                            f16* __restrict__ xf16) {
  __shared__ float tile[32][33];
  int bid = blockIdx.x, tid = threadIdx.x;
  if (bid < 6400) {
    int z = bid / 1600, rem = bid - z * 1600;
    int bx = rem % 40, by = rem / 40;
    const float* W = (z == 0) ? Wq : (z == 1) ? Wk : (z == 2) ? Wv : Wo;
    f16* Wt = (z < 3) ? (wqkv_t + (size_t)z * DD * DD) : wo_t;
    int tx = tid & 31, ty = tid >> 5;
    int n0 = bx * 32, k0 = by * 32;
#pragma unroll
    for (int i = 0; i < 32; i += 8)
      tile[ty + i][tx] = W[(size_t)(k0 + ty + i) * DD + n0 + tx];
    __syncthreads();
#pragma unroll
    for (int i = 0; i < 32; i += 8)
      Wt[(size_t)(n0 + ty + i) * DD + k0 + tx] = (f16)tile[tx][ty + i];
  } else {
    int i = (bid - 6400) * 256 + tid;   // 8 elems per thread
    float4 a = *(const float4*)&x[(size_t)i * 8];
    float4 b = *(const float4*)&x[(size_t)i * 8 + 4];
    f16x8 h = {(f16)a.x,(f16)a.y,(f16)a.z,(f16)a.w,(f16)b.x,(f16)b.y,(f16)b.z,(f16)b.w};
    *(f16x8*)&xf16[(size_t)i * 8] = h;
  }
}

// ---------------------------------------------------------------------------
// GEMM1: 8-phase counted-vmcnt 256x256 core (T1+T2+T3+T4+T5). BK=64 in 2
// K-halves of 32 cols; LDS = 2 slots x 2 khalf x (A 256x32 + B 256x32) =
// 128 KiB. Per K-tile: 4 phases of 16 MFMA. Counted vmcnt(4) only at K-tile
// boundaries (never 0 until the tail).
// R5 FIX (T2): slot = u ^ ((row>>1)&3)  [was u ^ (row&3), which aliased 4
// same-parity rows per slot -> 4-way bank conflict, measured 7.37M = exactly
// 4 extra cyc x 1.84M ds_read_b128]. New mapping: 16 lanes -> 8
// (parity,slot) groups x 2 lanes, alias pair at +512B = same bank = 2-way
// = free (m136). Both staging-source permutation and read swizzle updated
// (same involution, rule #21).
// ---------------------------------------------------------------------------
__global__ __launch_bounds__(512, 2) void gemm_qkv(const f16* __restrict__ Xh,
                                                   const f16* __restrict__ Wt,
                                                   const float* __restrict__ bq,
                                                   const float* __restrict__ bv,
                                                   f16* __restrict__ qbuf,
                                                   float* __restrict__ kout,
                                                   float* __restrict__ vout,
                                                   f16* __restrict__ kt16,
                                                   f16* __restrict__ vt16,
                                                   int use_f16) {
  __shared__ __align__(16) f16 AB[65536];   // A: [2 slot][2 khalf][8192], B at +32768
  int tid = threadIdx.x, w = tid >> 6, lane = tid & 63;
  int bid = blockIdx.x;
  int cX = bid & 7, rX = bid >> 3;          // rX in [0,60)
  int bm = cX * 4 + (rX & 3), bn = rX >> 2; // bm 0..31, bn 0..14 (XCD chunk, bm-fast)
  int m0 = bm * 256, n0 = bn * 256;
  int col16 = lane & 15, quad = lane >> 4;
  int wm = w >> 2, wn = w & 3;
  // staging geometry: per quarter-tile (256 rows x 32 cols, 16KB) each wave
  // issues 2 gload_lds covering rows w*32..w*32+31. LDS slot of lane =
  // (row lane>>2, slot lane&3); it must receive global chunk
  // u = slot ^ ((row>>1)&3) = (lane&3) ^ ((lane>>3)&3).
  int sRow = w * 32 + (lane >> 2);
  int sCg = (((lane & 3) ^ ((lane >> 3) & 3)) << 3);

  const f16* Ab = Xh + (size_t)m0 * DD;
  const f16* Bb = Wt + (size_t)n0 * DD;

  auto stA = [&](int kt, int kh, int sl) {
    const f16* g = Ab + (size_t)sRow * DD + kt * 64 + kh * 32 + sCg;
    f16* l = &AB[(sl * 2 + kh) * 8192 + w * 1024];
    async16(g, l);
    async16(g + (size_t)16 * DD, l + 512);
  };
  auto stB = [&](int kt, int kh, int sl) {
    const f16* g = Bb + (size_t)sRow * DD + kt * 64 + kh * 32 + sCg;
    f16* l = &AB[32768 + (sl * 2 + kh) * 8192 + w * 1024];
    async16(g, l);
    async16(g + (size_t)16 * DD, l + 512);
  };

  f32x4 acc[8][4] = {};
  f16x8 af[4], bf[4];

  auto lda = [&](int sl, int kh, int mh) {
#pragma unroll
    for (int i = 0; i < 4; ++i) {
      int row = wm * 128 + (mh * 4 + i) * 16 + col16;
      af[i] = *(const f16x8*)&AB[(sl * 2 + kh) * 8192 + row * 32 + ((quad ^ ((row >> 1) & 3)) << 3)];
    }
  };
  auto ldb = [&](int sl, int kh) {
#pragma unroll
    for (int i = 0; i < 4; ++i) {
      int row = wn * 64 + i * 16 + col16;
      bf[i] = *(const f16x8*)&AB[32768 + (sl * 2 + kh) * 8192 + row * 32 + ((quad ^ ((row >> 1) & 3)) << 3)];
    }
  };
  auto mf = [&](int mh) {
    __builtin_amdgcn_s_setprio(1);
#pragma unroll
    for (int i = 0; i < 4; ++i)
#pragma unroll
      for (int n = 0; n < 4; ++n)
        acc[mh * 4 + i][n] = __builtin_amdgcn_mfma_f32_16x16x32_f16(af[i], bf[n], acc[mh * 4 + i][n], 0, 0, 0);
    __builtin_amdgcn_s_setprio(0);
  };

  // prologue: t0 fully + t1's kh0 quarters; boundary invariant = steady state.
  stA(0, 0, 0); stB(0, 0, 0); stA(0, 1, 0); stB(0, 1, 0);
  stA(1, 0, 1); stB(1, 0, 1);
  asm volatile("s_waitcnt vmcnt(4)" ::: "memory");
  __builtin_amdgcn_s_barrier();

#pragma unroll 2
  for (int t = 0; t < NT; ++t) {
    int sl = t & 1;
    // phase 1: C(mi0-3, kh0)
    ldb(sl, 0); lda(sl, 0, 0);
    if (t + 1 < NT) stA(t + 1, 1, sl ^ 1);
    __builtin_amdgcn_s_barrier();
    mf(0);
    __builtin_amdgcn_sched_barrier(0);
    __builtin_amdgcn_s_barrier();
    // phase 2: C(mi4-7, kh0)  (bf reused)
    lda(sl, 0, 1);
    if (t + 1 < NT) stB(t + 1, 1, sl ^ 1);
    __builtin_amdgcn_s_barrier();
    mf(1);
    __builtin_amdgcn_sched_barrier(0);
    __builtin_amdgcn_s_barrier();
    // phase 3: C(mi0-3, kh1)   (quarter (sl,kh0) now dead -> stage t+2 kh0)
    ldb(sl, 1); lda(sl, 1, 0);
    if (t + 2 < NT) stA(t + 2, 0, sl);
    __builtin_amdgcn_s_barrier();
    mf(0);
    __builtin_amdgcn_sched_barrier(0);
    __builtin_amdgcn_s_barrier();
    // phase 4: C(mi4-7, kh1)
    lda(sl, 1, 1);
    if (t + 2 < NT) stB(t + 2, 0, sl);
    __builtin_amdgcn_s_barrier();
    mf(1);
    __builtin_amdgcn_sched_barrier(0);
    // K-tile boundary: counted vmcnt folded into trailing barrier.
    if (t < NT - 1) {
      if (t + 2 < NT) asm volatile("s_waitcnt vmcnt(4)" ::: "memory");
      else            asm volatile("s_waitcnt vmcnt(0)" ::: "memory");
      __builtin_amdgcn_s_barrier();
    }
  }

  // epilogue: q/k/v regions (bn/5).
  int region = bn / 5, nb = (bn % 5) * 256;
  int bB = m0 >> 10, t0 = m0 & 1023;        // 256-row tiles never cross batch
  if (region == 0) {            // q -> qbuf f16 [b][h][t][d], scale folded
#pragma unroll
    for (int mi = 0; mi < 8; ++mi)
#pragma unroll
      for (int ni = 0; ni < 4; ++ni) {
        int nl = nb + wn * 64 + ni * 16 + col16;
        int hh = nl >> 6, dd = nl & 63;
        float bb = bq[nl];
        int trow = t0 + wm * 128 + mi * 16 + quad * 4;
        size_t base = (((size_t)bB * HH + hh) * TT + trow) * 64 + dd;
#pragma unroll
        for (int r2 = 0; r2 < 4; ++r2)
          qbuf[base + (size_t)r2 * 64] = (f16)((acc[mi][ni][r2] + bb) * 0.125f);
      }
  } else if (region == 1) {     // k -> kout fp32 (+ kt16 f16 [b][h][t][d])
#pragma unroll
    for (int mi = 0; mi < 8; ++mi)
#pragma unroll
      for (int ni = 0; ni < 4; ++ni) {
        int nl = nb + wn * 64 + ni * 16 + col16;
        int hh = nl >> 6, dd = nl & 63;
        int trow = t0 + wm * 128 + mi * 16 + quad * 4;
        size_t mrow = (size_t)(m0 + wm * 128 + mi * 16 + quad * 4) * DD + nl;
        size_t base = (((size_t)bB * HH + hh) * TT + trow) * 64 + dd;
#pragma unroll
        for (int r2 = 0; r2 < 4; ++r2) {
          float vv = acc[mi][ni][r2];
          kout[mrow + (size_t)r2 * DD] = vv;
          if (use_f16) kt16[base + (size_t)r2 * 64] = (f16)vv;
        }
      }
  } else {                      // v -> vout fp32 +bv (+ vt16 f16 [b][h][d][t])
#pragma unroll
    for (int mi = 0; mi < 8; ++mi)
#pragma unroll
      for (int ni = 0; ni < 4; ++ni) {
        int nl = nb + wn * 64 + ni * 16 + col16;
        int hh = nl >> 6, dd = nl & 63;
        float bb = bv[nl];
        int trow = t0 + wm * 128 + mi * 16 + quad * 4;
        size_t mrow = (size_t)(m0 + wm * 128 + mi * 16 + quad * 4) * DD + nl;
        f16x4 pk;
#pragma unroll
        for (int r2 = 0; r2 < 4; ++r2) {
          float vv = acc[mi][ni][r2] + bb;
          vout[mrow + (size_t)r2 * DD] = vv;
          pk[r2] = (f16)vv;
        }
        if (use_f16)
          *(f16x4*)&vt16[(((size_t)bB * HH + hh) * 64 + dd) * TT + trow] = pk;
      }
  }
}

// ---------------------------------------------------------------------------
// Flash attention (unchanged from R3: dbuf K/V, counted vmcnt, setprio, T1).
// ---------------------------------------------------------------------------
__global__ __launch_bounds__(256) void attn(const f16* __restrict__ qbuf,
                                            const f16* __restrict__ kt16,
                                            const f16* __restrict__ vt16,
                                            const float* __restrict__ kout,
                                            const float* __restrict__ vout,
                                            f16* __restrict__ wv,
                                            int use_f16) {
  __shared__ f16 Ks[2][64 * 64];
  __shared__ f16 Vt[2][64 * 64];
  __shared__ f16 Pw[4][32 * 64];
  int bid = blockIdx.x;
  int s_ = (bid & 7) * 160 + (bid >> 3);
  int qt = 7 - (s_ & 7);
  int bh = s_ >> 3;
  int h = bh % 20, b = bh / 20;
  int tid = threadIdx.x, w = tid >> 6, lane = tid & 63;
  int col16 = lane & 15, quad = lane >> 4;
  int c7 = col16 & 7;

  const f16* Qh = qbuf + (((size_t)b * HH + h) * TT + qt * 128 + w * 32) * 64;
  f16x8 qf[2][2];
#pragma unroll
  for (int ni = 0; ni < 2; ++ni)
#pragma unroll
    for (int kh = 0; kh < 2; ++kh)
      qf[ni][kh] = *(const f16x8*)&Qh[(ni * 16 + col16) * 64 + kh * 32 + quad * 8];

  float m_run[2] = {-1e30f, -1e30f}, l_run[2] = {0.f, 0.f};
  f32x4 accO[2][4] = {};
  int jt_end = 2 * qt + 2;
  int my_end = 2 * qt + 1 + (w >> 1);
  const f16* Ktg = kt16 + (((size_t)b * HH + h) * TT) * 64;
  const f16* Vtg = vt16 + (((size_t)b * HH + h) * 64) * TT;
  const float* Kg = kout + ((size_t)b * TT) * DD + h * 64;
  const float* Vg = vout + ((size_t)b * TT) * DD + h * 64;

  auto stage = [&](int jt, int pb) {
    if (use_f16) {
#pragma unroll
      for (int t = 0; t < 2; ++t) {
        int j = w * 16 + t * 8 + (lane >> 3);
        int cg = (lane & 7) ^ (j & 7);
        async16(&Ktg[(size_t)(jt * 64 + j) * 64 + cg * 8], &Ks[pb][w * 1024 + t * 512]);
        async16(&Vtg[(size_t)j * TT + jt * 64 + cg * 8], &Vt[pb][w * 1024 + t * 512]);
      }
    } else {
#pragma unroll
      for (int i = 0; i < 4; ++i) {
        int g = tid + i * 256;
        int j = g >> 4, c4 = (g & 15) * 4;
        float4 kv = *(const float4*)&Kg[(size_t)(jt * 64 + j) * DD + c4];
        f16x4 k4 = {(f16)kv.x, (f16)kv.y, (f16)kv.z, (f16)kv.w};
        *(f16x4*)&Ks[pb][j * 64 + (((c4 >> 3) ^ (j & 7)) * 8) + (c4 & 7)] = k4;
        float4 vv = *(const float4*)&Vg[(size_t)(jt * 64 + j) * DD + c4];
        int ch = (j >> 3), jo = j & 7;
        Vt[pb][(c4 + 0) * 64 + ((ch ^ ((c4 + 0) & 7)) * 8) + jo] = (f16)vv.x;
        Vt[pb][(c4 + 1) * 64 + ((ch ^ ((c4 + 1) & 7)) * 8) + jo] = (f16)vv.y;
        Vt[pb][(c4 + 2) * 64 + ((ch ^ ((c4 + 2) & 7)) * 8) + jo] = (f16)vv.z;
        Vt[pb][(c4 + 3) * 64 + ((ch ^ ((c4 + 3) & 7)) * 8) + jo] = (f16)vv.w;
      }
    }
  };

  stage(0, 0);
  for (int jt = 0; jt < jt_end; ++jt) {
    int pb = jt & 1;
    if (jt + 1 < jt_end) {
      stage(jt + 1, pb ^ 1);
      asm volatile("s_waitcnt vmcnt(4) lgkmcnt(0)\n\ts_barrier" ::: "memory");
    } else {
      asm volatile("s_waitcnt vmcnt(0) lgkmcnt(0)\n\ts_barrier" ::: "memory");
    }

    if (jt < my_end) {
      f32x4 s[4][2] = {};
      __builtin_amdgcn_s_setprio(1);
#pragma unroll
      for (int mj = 0; mj < 4; ++mj)
#pragma unroll
        for (int kh = 0; kh < 2; ++kh) {
          f16x8 ak = *(f16x8*)&Ks[pb][(mj * 16 + col16) * 64 + (((kh * 4 + quad) ^ c7) * 8)];
#pragma unroll
          for (int ni = 0; ni < 2; ++ni)
            s[mj][ni] = __builtin_amdgcn_mfma_f32_16x16x32_f16(ak, qf[ni][kh], s[mj][ni], 0, 0, 0);
        }
      __builtin_amdgcn_s_setprio(0);
      if (jt * 64 + 63 > qt * 128 + w * 32) {
#pragma unroll
        for (int mj = 0; mj < 4; ++mj)
#pragma unroll
          for (int ni = 0; ni < 2; ++ni) {
            int qg = qt * 128 + w * 32 + ni * 16 + col16;
#pragma unroll
            for (int r = 0; r < 4; ++r) {
              int jg = jt * 64 + mj * 16 + quad * 4 + r;
              if (jg > qg) s[mj][ni][r] = -1e30f;
            }
          }
      }
      float alpha[2];
#pragma unroll
      for (int ni = 0; ni < 2; ++ni) {
        float mx = -1e30f;
#pragma unroll
        for (int mj = 0; mj < 4; ++mj)
#pragma unroll
          for (int r = 0; r < 4; ++r) mx = fmaxf(mx, s[mj][ni][r]);
        mx = fmaxf(mx, __shfl_xor(mx, 16));
        mx = fmaxf(mx, __shfl_xor(mx, 32));
        float mnew = fmaxf(m_run[ni], mx);
        float al = __expf(m_run[ni] - mnew);
        float ssum = 0.f;
#pragma unroll
        for (int mj = 0; mj < 4; ++mj)
#pragma unroll
          for (int r = 0; r < 4; ++r) {
            float p = __expf(s[mj][ni][r] - mnew);
            ssum += p;
            int j = mj * 16 + quad * 4 + r;
            Pw[w][(ni * 16 + col16) * 64 + (((j >> 3) ^ c7) * 8) + (j & 7)] = (f16)p;
          }
        ssum += __shfl_xor(ssum, 16);
        ssum += __shfl_xor(ssum, 32);
        l_run[ni] = l_run[ni] * al + ssum;
        m_run[ni] = mnew;
        alpha[ni] = al;
      }
#pragma unroll
      for (int mi = 0; mi < 2; ++mi)
#pragma unroll
        for (int r = 0; r < 4; ++r) {
          float a_o = __shfl(alpha[mi], quad * 4 + r);
#pragma unroll
          for (int dsub = 0; dsub < 4; ++dsub) accO[mi][dsub][r] *= a_o;
        }
      f16x8 ap[2][2];
#pragma unroll
      for (int mi = 0; mi < 2; ++mi)
#pragma unroll
        for (int kh = 0; kh < 2; ++kh)
          ap[mi][kh] = *(f16x8*)&Pw[w][(mi * 16 + col16) * 64 + (((kh * 4 + quad) ^ c7) * 8)];
      __builtin_amdgcn_s_setprio(1);
#pragma unroll
      for (int dsub = 0; dsub < 4; ++dsub)
#pragma unroll
        for (int kh = 0; kh < 2; ++kh) {
          f16x8 bvv = *(f16x8*)&Vt[pb][(dsub * 16 + col16) * 64 + (((kh * 4 + quad) ^ c7) * 8)];
#pragma unroll
          for (int mi = 0; mi < 2; ++mi)
            accO[mi][dsub] = __builtin_amdgcn_mfma_f32_16x16x32_f16(ap[mi][kh], bvv, accO[mi][dsub], 0, 0, 0);
        }
      __builtin_amdgcn_s_setprio(0);
    }
    asm volatile("s_barrier" ::: "memory");
  }
  size_t orow = ((size_t)b * TT + qt * 128 + w * 32) * DD + h * 64;
#pragma unroll
  for (int mi = 0; mi < 2; ++mi)
#pragma unroll
    for (int r = 0; r < 4; ++r) {
      float lo = __shfl(l_run[mi], quad * 4 + r);
      float rl = 1.0f / lo;
      int t = mi * 16 + quad * 4 + r;
#pragma unroll
      for (int dsub = 0; dsub < 4; ++dsub)
        wv[orow + (size_t)t * DD + dsub * 16 + col16] = (f16)(accO[mi][dsub][r] * rl);
    }
}

// ---------------------------------------------------------------------------
// GEMM2 (unchanged m97 core — in-run comparator vs the new 8-phase core).
// ---------------------------------------------------------------------------
__global__ __launch_bounds__(256, 4) void gemm_out(const f16* __restrict__ A,
                                                   const f16* __restrict__ Wt,
                                                   const float* __restrict__ bo,
                                                   float* __restrict__ out) {
  __shared__ f16 As[128 * 64];
  __shared__ f16 Bs[128 * 64];
  int tid = threadIdx.x, w = tid >> 6, lane = tid & 63;
  int bid = blockIdx.x;
  int c = bid & 7, r = bid >> 3;          // r in [0,80)
  int bm = c * 8 + (r & 7), bn = r >> 3;  // bm in [0,64), bn in [0,10)
  int m0 = bm * 128, n0 = bn * 128;
  int col16 = lane & 15, quad = lane >> 4;
  int wm = (w >> 1) * 64, wn = (w & 1) * 64;
  int rowS[4], cgS[4];
#pragma unroll
  for (int t = 0; t < 4; ++t) {
    int L = w * 256 + t * 64 + lane;
    rowS[t] = L >> 3;
    cgS[t] = (L & 7) ^ ((L >> 3) & 7);
  }
  f32x4 acc[4][4] = {};
  for (int k0 = 0; k0 < DD; k0 += 64) {
#pragma unroll
    for (int t = 0; t < 4; ++t) {
      async16(&A[(size_t)(m0 + rowS[t]) * DD + k0 + cgS[t] * 8], &As[(w * 4 + t) * 512]);
      async16(&Wt[(size_t)(n0 + rowS[t]) * DD + k0 + cgS[t] * 8], &Bs[(w * 4 + t) * 512]);
    }
    __syncthreads();
    f16x8 af[4][2], bf[4][2];
#pragma unroll
    for (int mi = 0; mi < 4; ++mi) {
      int m = wm + mi * 16 + col16;
#pragma unroll
      for (int kh = 0; kh < 2; ++kh)
        af[mi][kh] = *(f16x8*)&As[m * 64 + (((kh * 4 + quad) ^ (m & 7)) * 8)];
    }
#pragma unroll
    for (int ni = 0; ni < 4; ++ni) {
      int n = wn + ni * 16 + col16;
#pragma unroll
      for (int kh = 0; kh < 2; ++kh)
        bf[ni][kh] = *(f16x8*)&Bs[n * 64 + (((kh * 4 + quad) ^ (n & 7)) * 8)];
    }
#pragma unroll
    for (int kh = 0; kh < 2; ++kh)
#pragma unroll
      for (int mi = 0; mi < 4; ++mi)
#pragma unroll
        for (int ni = 0; ni < 4; ++ni)
          acc[mi][ni] = __builtin_amdgcn_mfma_f32_16x16x32_f16(af[mi][kh], bf[ni][kh], acc[mi][ni], 0, 0, 0);
    __syncthreads();
  }
#pragma unroll
  for (int mi = 0; mi < 4; ++mi)
#pragma unroll
    for (int ni = 0; ni < 4; ++ni) {
      int n = n0 + wn + ni * 16 + col16;
      float bias = bo[n];
      size_t mrow = (size_t)(m0 + wm + mi * 16 + quad * 4) * DD + n;
#pragma unroll
      for (int r2 = 0; r2 < 4; ++r2)
        out[mrow + (size_t)r2 * DD] = acc[mi][ni][r2] + bias;
    }
}

// ---------------------------------------------------------------------------
extern "C" void kernel_launch(void* const* d_in, const int* in_sizes, int n_in,
                              void* d_out, int out_size, void* d_ws, size_t ws_size,
                              hipStream_t stream) {
  const float* x  = (const float*)d_in[0];
  const float* Wq = (const float*)d_in[4];
  const float* bq = (const float*)d_in[5];
  const float* Wk = (const float*)d_in[6];
  const float* Wv = (const float*)d_in[7];
  const float* bv = (const float*)d_in[8];
  const float* Wo = (const float*)d_in[9];
  const float* bo = (const float*)d_in[10];

  float* out  = (float*)d_out;
  float* kout = out + (size_t)MM * DD;
  float* vout = out + 2 * (size_t)MM * DD;

  // ws layout (bytes): wqkv_t 0 | wo_t 9,830,400 | xf16/wv 13,107,200 |
  // qbuf 34,078,720 | vt16 55,050,240 | kt16 76,021,760 -> 96,993,280 total
  char* ws = (char*)d_ws;
  f16* wqkv_t = (f16*)(ws);
  f16* wo_t   = (f16*)(ws + 9830400);
  f16* xf16   = (f16*)(ws + 13107200);
  f16* wvbuf  = (f16*)(ws + 13107200);
  f16* qbuf   = (f16*)(ws + 34078720);
  f16* vt16   = (f16*)(ws + 55050240);
  f16* kt16   = (f16*)(ws + 76021760);
  int use_f16 = (ws_size >= (size_t)96993280) ? 1 : 0;

  prep<<<dim3(11520), 256, 0, stream>>>(Wq, Wk, Wv, Wo, x, wqkv_t, wo_t, xf16);

  gemm_qkv<<<dim3(480), 512, 0, stream>>>(xf16, wqkv_t, bq, bv, qbuf, kout, vout, kt16, vt16, use_f16);
  attn<<<dim3(1280), 256, 0, stream>>>(qbuf, kt16, vt16, kout, vout, wvbuf, use_f16);
  gemm_out<<<dim3(640), 256, 0, stream>>>(wvbuf, wo_t, bo, out);
}

// Round 8
// 421.736 us; speedup vs baseline: 1.0374x; 1.0374x over previous
//
#include <hip/hip_runtime.h>

// Whisper-style self-attention, B=8 T=1024 D=1280 H=20 DH=64, fp32 I/O.
#define BB 8
#define TT 1024
#define DD 1280
#define HH 20
#define DHH 64
#define MM (BB*TT)      // 8192 rows

typedef _Float16 f16;
typedef f16 f16x8 __attribute__((ext_vector_type(8)));
typedef f16 f16x4 __attribute__((ext_vector_type(4)));
typedef float f32x4 __attribute__((ext_vector_type(4)));

// async global->LDS, 16B per lane. LDS dest = wave-uniform base + lane*16.
__device__ __forceinline__ void async16(const f16* g, f16* l) {
  __builtin_amdgcn_global_load_lds((const __attribute__((address_space(1))) void*)g,
                                   (__attribute__((address_space(3))) void*)l, 16, 0, 0);
}

// ---------------------------------------------------------------------------
// prep: fused {Wq,Wk,Wv,Wo transpose+cast} and {x fp32->f16}.
// ---------------------------------------------------------------------------
__global__ __launch_bounds__(256) void prep(const float* __restrict__ Wq,
                                            const float* __restrict__ Wk,
                                            const float* __restrict__ Wv,
                                            const float* __restrict__ Wo,
                                            const float* __restrict__ x,
                                            f16* __restrict__ wqkv_t,
                                            f16* __restrict__ wo_t,
                                            f16* __restrict__ xf16) {
  __shared__ float tile[32][33];
  int bid = blockIdx.x, tid = threadIdx.x;
  if (bid < 6400) {
    int z = bid / 1600, rem = bid - z * 1600;
    int bx = rem % 40, by = rem / 40;
    const float* W = (z == 0) ? Wq : (z == 1) ? Wk : (z == 2) ? Wv : Wo;
    f16* Wt = (z < 3) ? (wqkv_t + (size_t)z * DD * DD) : wo_t;
    int tx = tid & 31, ty = tid >> 5;
    int n0 = bx * 32, k0 = by * 32;
#pragma unroll
    for (int i = 0; i < 32; i += 8)
      tile[ty + i][tx] = W[(size_t)(k0 + ty + i) * DD + n0 + tx];
    __syncthreads();
#pragma unroll
    for (int i = 0; i < 32; i += 8)
      Wt[(size_t)(n0 + ty + i) * DD + k0 + tx] = (f16)tile[tx][ty + i];
  } else {
    int i = (bid - 6400) * 256 + tid;   // 8 elems per thread
    float4 a = *(const float4*)&x[(size_t)i * 8];
    float4 b = *(const float4*)&x[(size_t)i * 8 + 4];
    f16x8 h = {(f16)a.x,(f16)a.y,(f16)a.z,(f16)a.w,(f16)b.x,(f16)b.y,(f16)b.z,(f16)b.w};
    *(f16x8*)&xf16[(size_t)i * 8] = h;
  }
}

// ---------------------------------------------------------------------------
// GEMM1 (R3 m97 core: 128x128 tile, BK=64, global_load_lds, XOR-swizzled
// LDS, XCD-aware bijective swizzle; verified ~100us, FETCH 77MB, 0 conflicts)
// ---------------------------------------------------------------------------
__global__ __launch_bounds__(256, 4) void gemm_qkv(const f16* __restrict__ Xh,
                                                   const f16* __restrict__ Wt,
                                                   const float* __restrict__ bq,
                                                   const float* __restrict__ bv,
                                                   f16* __restrict__ qbuf,
                                                   float* __restrict__ kout,
                                                   float* __restrict__ vout,
                                                   f16* __restrict__ kt16,
                                                   f16* __restrict__ vt16,
                                                   int use_f16) {
  __shared__ f16 As[128 * 64];
  __shared__ f16 Bs[128 * 64];
  int tid = threadIdx.x, w = tid >> 6, lane = tid & 63;
  int bid = blockIdx.x;
  int c = bid & 7, r = bid >> 3;          // r in [0,240)
  int bm = c * 8 + (r & 7), bn = r >> 3;  // bm in [0,64), bn in [0,30)
  int m0 = bm * 128, n0 = bn * 128;
  int col16 = lane & 15, quad = lane >> 4;
  int wm = (w >> 1) * 64, wn = (w & 1) * 64;
  int rowS[4], cgS[4];
#pragma unroll
  for (int t = 0; t < 4; ++t) {
    int L = w * 256 + t * 64 + lane;
    rowS[t] = L >> 3;
    cgS[t] = (L & 7) ^ ((L >> 3) & 7);
  }
  f32x4 acc[4][4] = {};
  for (int k0 = 0; k0 < DD; k0 += 64) {
#pragma unroll
    for (int t = 0; t < 4; ++t) {
      async16(&Xh[(size_t)(m0 + rowS[t]) * DD + k0 + cgS[t] * 8], &As[(w * 4 + t) * 512]);
      async16(&Wt[(size_t)(n0 + rowS[t]) * DD + k0 + cgS[t] * 8], &Bs[(w * 4 + t) * 512]);
    }
    __syncthreads();
    f16x8 af[4][2], bf[4][2];
#pragma unroll
    for (int mi = 0; mi < 4; ++mi) {
      int m = wm + mi * 16 + col16;
#pragma unroll
      for (int kh = 0; kh < 2; ++kh)
        af[mi][kh] = *(f16x8*)&As[m * 64 + (((kh * 4 + quad) ^ (m & 7)) * 8)];
    }
#pragma unroll
    for (int ni = 0; ni < 4; ++ni) {
      int n = wn + ni * 16 + col16;
#pragma unroll
      for (int kh = 0; kh < 2; ++kh)
        bf[ni][kh] = *(f16x8*)&Bs[n * 64 + (((kh * 4 + quad) ^ (n & 7)) * 8)];
    }
#pragma unroll
    for (int kh = 0; kh < 2; ++kh)
#pragma unroll
      for (int mi = 0; mi < 4; ++mi)
#pragma unroll
        for (int ni = 0; ni < 4; ++ni)
          acc[mi][ni] = __builtin_amdgcn_mfma_f32_16x16x32_f16(af[mi][kh], bf[ni][kh], acc[mi][ni], 0, 0, 0);
    __syncthreads();
  }

  int region = bn / 10, nb = (bn % 10) * 128;
  int bB = m0 >> 10;            // 128-row tiles never cross a batch boundary
  int t0 = m0 & 1023;
  if (region == 0) {            // q
#pragma unroll
    for (int mi = 0; mi < 4; ++mi)
#pragma unroll
      for (int ni = 0; ni < 4; ++ni) {
        int n = nb + wn + ni * 16 + col16;
        int hh = n >> 6, dd = n & 63;
        float bb = bq[n];
        size_t base = (((size_t)bB * HH + hh) * TT + (t0 + wm + mi * 16 + quad * 4)) * 64 + dd;
#pragma unroll
        for (int r2 = 0; r2 < 4; ++r2)
          qbuf[base + (size_t)r2 * 64] = (f16)((acc[mi][ni][r2] + bb) * 0.125f);
      }
  } else if (region == 1) {     // k
#pragma unroll
    for (int mi = 0; mi < 4; ++mi)
#pragma unroll
      for (int ni = 0; ni < 4; ++ni) {
        int n = nb + wn + ni * 16 + col16;
        int hh = n >> 6, dd = n & 63;
        size_t mrow = (size_t)(m0 + wm + mi * 16 + quad * 4) * DD + n;
        size_t base = (((size_t)bB * HH + hh) * TT + (t0 + wm + mi * 16 + quad * 4)) * 64 + dd;
#pragma unroll
        for (int r2 = 0; r2 < 4; ++r2) {
          float vv = acc[mi][ni][r2];
          kout[mrow + (size_t)r2 * DD] = vv;
          if (use_f16) kt16[base + (size_t)r2 * 64] = (f16)vv;
        }
      }
  } else {                      // v
#pragma unroll
    for (int mi = 0; mi < 4; ++mi)
#pragma unroll
      for (int ni = 0; ni < 4; ++ni) {
        int n = nb + wn + ni * 16 + col16;
        int hh = n >> 6, dd = n & 63;
        float bb = bv[n];
        size_t mrow = (size_t)(m0 + wm + mi * 16 + quad * 4) * DD + n;
        f16x4 pk;
#pragma unroll
        for (int r2 = 0; r2 < 4; ++r2) {
          float vv = acc[mi][ni][r2] + bb;
          vout[mrow + (size_t)r2 * DD] = vv;
          pk[r2] = (f16)vv;
        }
        if (use_f16)
          *(f16x4*)&vt16[(((size_t)bB * HH + hh) * 64 + dd) * TT + t0 + wm + mi * 16 + quad * 4] = pk;
      }
  }
}

// ---------------------------------------------------------------------------
// Flash attention (R3 base: dbuf K/V, counted vmcnt, setprio, T1 swizzle).
// R7/R8: P-store vectorized. Within one mj, the 4 exp values share one
// swizzled 8-f16 chunk: j = mj*16+quad*4+r -> j>>3 = mj*2+(quad>>1)
// (r-invariant), j&7 = (quad&1)*4+r (contiguous). So 32 scalar ds_write_u16
// per lane per tile collapse to 8 ds_write_b64 (audited: in-bounds, 8B
// aligned, lane-disjoint; same XOR bank spread).
// ---------------------------------------------------------------------------
__global__ __launch_bounds__(256) void attn(const f16* __restrict__ qbuf,
                                            const f16* __restrict__ kt16,
                                            const f16* __restrict__ vt16,
                                            const float* __restrict__ kout,
                                            const float* __restrict__ vout,
                                            f16* __restrict__ wv,
                                            int use_f16) {
  __shared__ f16 Ks[2][64 * 64];
  __shared__ f16 Vt[2][64 * 64];
  __shared__ f16 Pw[4][32 * 64];
  int bid = blockIdx.x;
  int s_ = (bid & 7) * 160 + (bid >> 3);
  int qt = 7 - (s_ & 7);
  int bh = s_ >> 3;
  int h = bh % 20, b = bh / 20;
  int tid = threadIdx.x, w = tid >> 6, lane = tid & 63;
  int col16 = lane & 15, quad = lane >> 4;
  int c7 = col16 & 7;

  const f16* Qh = qbuf + (((size_t)b * HH + h) * TT + qt * 128 + w * 32) * 64;
  f16x8 qf[2][2];
#pragma unroll
  for (int ni = 0; ni < 2; ++ni)
#pragma unroll
    for (int kh = 0; kh < 2; ++kh)
      qf[ni][kh] = *(const f16x8*)&Qh[(ni * 16 + col16) * 64 + kh * 32 + quad * 8];

  float m_run[2] = {-1e30f, -1e30f}, l_run[2] = {0.f, 0.f};
  f32x4 accO[2][4] = {};
  int jt_end = 2 * qt + 2;
  int my_end = 2 * qt + 1 + (w >> 1);
  const f16* Ktg = kt16 + (((size_t)b * HH + h) * TT) * 64;
  const f16* Vtg = vt16 + (((size_t)b * HH + h) * 64) * TT;
  const float* Kg = kout + ((size_t)b * TT) * DD + h * 64;
  const float* Vg = vout + ((size_t)b * TT) * DD + h * 64;

  auto stage = [&](int jt, int pb) {
    if (use_f16) {
#pragma unroll
      for (int t = 0; t < 2; ++t) {
        int j = w * 16 + t * 8 + (lane >> 3);
        int cg = (lane & 7) ^ (j & 7);
        async16(&Ktg[(size_t)(jt * 64 + j) * 64 + cg * 8], &Ks[pb][w * 1024 + t * 512]);
        async16(&Vtg[(size_t)j * TT + jt * 64 + cg * 8], &Vt[pb][w * 1024 + t * 512]);
      }
    } else {
#pragma unroll
      for (int i = 0; i < 4; ++i) {
        int g = tid + i * 256;
        int j = g >> 4, c4 = (g & 15) * 4;
        float4 kv = *(const float4*)&Kg[(size_t)(jt * 64 + j) * DD + c4];
        f16x4 k4 = {(f16)kv.x, (f16)kv.y, (f16)kv.z, (f16)kv.w};
        *(f16x4*)&Ks[pb][j * 64 + (((c4 >> 3) ^ (j & 7)) * 8) + (c4 & 7)] = k4;
        float4 vv = *(const float4*)&Vg[(size_t)(jt * 64 + j) * DD + c4];
        int ch = (j >> 3), jo = j & 7;
        Vt[pb][(c4 + 0) * 64 + ((ch ^ ((c4 + 0) & 7)) * 8) + jo] = (f16)vv.x;
        Vt[pb][(c4 + 1) * 64 + ((ch ^ ((c4 + 1) & 7)) * 8) + jo] = (f16)vv.y;
        Vt[pb][(c4 + 2) * 64 + ((ch ^ ((c4 + 2) & 7)) * 8) + jo] = (f16)vv.z;
        Vt[pb][(c4 + 3) * 64 + ((ch ^ ((c4 + 3) & 7)) * 8) + jo] = (f16)vv.w;
      }
    }
  };

  stage(0, 0);
  for (int jt = 0; jt < jt_end; ++jt) {
    int pb = jt & 1;
    if (jt + 1 < jt_end) {
      stage(jt + 1, pb ^ 1);
      asm volatile("s_waitcnt vmcnt(4) lgkmcnt(0)\n\ts_barrier" ::: "memory");
    } else {
      asm volatile("s_waitcnt vmcnt(0) lgkmcnt(0)\n\ts_barrier" ::: "memory");
    }

    if (jt < my_end) {
      f32x4 s[4][2] = {};
      __builtin_amdgcn_s_setprio(1);
#pragma unroll
      for (int mj = 0; mj < 4; ++mj)
#pragma unroll
        for (int kh = 0; kh < 2; ++kh) {
          f16x8 ak = *(f16x8*)&Ks[pb][(mj * 16 + col16) * 64 + (((kh * 4 + quad) ^ c7) * 8)];
#pragma unroll
          for (int ni = 0; ni < 2; ++ni)
            s[mj][ni] = __builtin_amdgcn_mfma_f32_16x16x32_f16(ak, qf[ni][kh], s[mj][ni], 0, 0, 0);
        }
      __builtin_amdgcn_s_setprio(0);
      if (jt * 64 + 63 > qt * 128 + w * 32) {
#pragma unroll
        for (int mj = 0; mj < 4; ++mj)
#pragma unroll
          for (int ni = 0; ni < 2; ++ni) {
            int qg = qt * 128 + w * 32 + ni * 16 + col16;
#pragma unroll
            for (int r = 0; r < 4; ++r) {
              int jg = jt * 64 + mj * 16 + quad * 4 + r;
              if (jg > qg) s[mj][ni][r] = -1e30f;
            }
          }
      }
      float alpha[2];
#pragma unroll
      for (int ni = 0; ni < 2; ++ni) {
        float mx = -1e30f;
#pragma unroll
        for (int mj = 0; mj < 4; ++mj)
#pragma unroll
          for (int r = 0; r < 4; ++r) mx = fmaxf(mx, s[mj][ni][r]);
        mx = fmaxf(mx, __shfl_xor(mx, 16));
        mx = fmaxf(mx, __shfl_xor(mx, 32));
        float mnew = fmaxf(m_run[ni], mx);
        float al = __expf(m_run[ni] - mnew);
        float ssum = 0.f;
#pragma unroll
        for (int mj = 0; mj < 4; ++mj) {
          f16x4 pk;
#pragma unroll
          for (int r = 0; r < 4; ++r) {
            float p = __expf(s[mj][ni][r] - mnew);
            ssum += p;
            pk[r] = (f16)p;
          }
          // one b64 store replaces 4 scalar u16 stores (see header comment)
          int ch = (mj * 2 + (quad >> 1)) ^ c7;
          *(f16x4*)&Pw[w][(ni * 16 + col16) * 64 + ch * 8 + (quad & 1) * 4] = pk;
        }
        ssum += __shfl_xor(ssum, 16);
        ssum += __shfl_xor(ssum, 32);
        l_run[ni] = l_run[ni] * al + ssum;
        m_run[ni] = mnew;
        alpha[ni] = al;
      }
#pragma unroll
      for (int mi = 0; mi < 2; ++mi)
#pragma unroll
        for (int r = 0; r < 4; ++r) {
          float a_o = __shfl(alpha[mi], quad * 4 + r);
#pragma unroll
          for (int dsub = 0; dsub < 4; ++dsub) accO[mi][dsub][r] *= a_o;
        }
      f16x8 ap[2][2];
#pragma unroll
      for (int mi = 0; mi < 2; ++mi)
#pragma unroll
        for (int kh = 0; kh < 2; ++kh)
          ap[mi][kh] = *(f16x8*)&Pw[w][(mi * 16 + col16) * 64 + (((kh * 4 + quad) ^ c7) * 8)];
      __builtin_amdgcn_s_setprio(1);
#pragma unroll
      for (int dsub = 0; dsub < 4; ++dsub)
#pragma unroll
        for (int kh = 0; kh < 2; ++kh) {
          f16x8 bvv = *(f16x8*)&Vt[pb][(dsub * 16 + col16) * 64 + (((kh * 4 + quad) ^ c7) * 8)];
#pragma unroll
          for (int mi = 0; mi < 2; ++mi)
            accO[mi][dsub] = __builtin_amdgcn_mfma_f32_16x16x32_f16(ap[mi][kh], bvv, accO[mi][dsub], 0, 0, 0);
        }
      __builtin_amdgcn_s_setprio(0);
    }
    asm volatile("s_barrier" ::: "memory");
  }
  size_t orow = ((size_t)b * TT + qt * 128 + w * 32) * DD + h * 64;
#pragma unroll
  for (int mi = 0; mi < 2; ++mi)
#pragma unroll
    for (int r = 0; r < 4; ++r) {
      float lo = __shfl(l_run[mi], quad * 4 + r);
      float rl = 1.0f / lo;
      int t = mi * 16 + quad * 4 + r;
#pragma unroll
      for (int dsub = 0; dsub < 4; ++dsub)
        wv[orow + (size_t)t * DD + dsub * 16 + col16] = (f16)(accO[mi][dsub][r] * rl);
    }
}

// ---------------------------------------------------------------------------
// GEMM2 (unchanged m97 core, XCD swizzle).
// ---------------------------------------------------------------------------
__global__ __launch_bounds__(256, 4) void gemm_out(const f16* __restrict__ A,
                                                   const f16* __restrict__ Wt,
                                                   const float* __restrict__ bo,
                                                   float* __restrict__ out) {
  __shared__ f16 As[128 * 64];
  __shared__ f16 Bs[128 * 64];
  int tid = threadIdx.x, w = tid >> 6, lane = tid & 63;
  int bid = blockIdx.x;
  int c = bid & 7, r = bid >> 3;          // r in [0,80)
  int bm = c * 8 + (r & 7), bn = r >> 3;  // bm in [0,64), bn in [0,10)
  int m0 = bm * 128, n0 = bn * 128;
  int col16 = lane & 15, quad = lane >> 4;
  int wm = (w >> 1) * 64, wn = (w & 1) * 64;
  int rowS[4], cgS[4];
#pragma unroll
  for (int t = 0; t < 4; ++t) {
    int L = w * 256 + t * 64 + lane;
    rowS[t] = L >> 3;
    cgS[t] = (L & 7) ^ ((L >> 3) & 7);
  }
  f32x4 acc[4][4] = {};
  for (int k0 = 0; k0 < DD; k0 += 64) {
#pragma unroll
    for (int t = 0; t < 4; ++t) {
      async16(&A[(size_t)(m0 + rowS[t]) * DD + k0 + cgS[t] * 8], &As[(w * 4 + t) * 512]);
      async16(&Wt[(size_t)(n0 + rowS[t]) * DD + k0 + cgS[t] * 8], &Bs[(w * 4 + t) * 512]);
    }
    __syncthreads();
    f16x8 af[4][2], bf[4][2];
#pragma unroll
    for (int mi = 0; mi < 4; ++mi) {
      int m = wm + mi * 16 + col16;
#pragma unroll
      for (int kh = 0; kh < 2; ++kh)
        af[mi][kh] = *(f16x8*)&As[m * 64 + (((kh * 4 + quad) ^ (m & 7)) * 8)];
    }
#pragma unroll
    for (int ni = 0; ni < 4; ++ni) {
      int n = wn + ni * 16 + col16;
#pragma unroll
      for (int kh = 0; kh < 2; ++kh)
        bf[ni][kh] = *(f16x8*)&Bs[n * 64 + (((kh * 4 + quad) ^ (n & 7)) * 8)];
    }
#pragma unroll
    for (int kh = 0; kh < 2; ++kh)
#pragma unroll
      for (int mi = 0; mi < 4; ++mi)
#pragma unroll
        for (int ni = 0; ni < 4; ++ni)
          acc[mi][ni] = __builtin_amdgcn_mfma_f32_16x16x32_f16(af[mi][kh], bf[ni][kh], acc[mi][ni], 0, 0, 0);
    __syncthreads();
  }
#pragma unroll
  for (int mi = 0; mi < 4; ++mi)
#pragma unroll
    for (int ni = 0; ni < 4; ++ni) {
      int n = n0 + wn + ni * 16 + col16;
      float bias = bo[n];
      size_t mrow = (size_t)(m0 + wm + mi * 16 + quad * 4) * DD + n;
#pragma unroll
      for (int r2 = 0; r2 < 4; ++r2)
        out[mrow + (size_t)r2 * DD] = acc[mi][ni][r2] + bias;
    }
}

// ---------------------------------------------------------------------------
extern "C" void kernel_launch(void* const* d_in, const int* in_sizes, int n_in,
                              void* d_out, int out_size, void* d_ws, size_t ws_size,
                              hipStream_t stream) {
  const float* x  = (const float*)d_in[0];
  const float* Wq = (const float*)d_in[4];
  const float* bq = (const float*)d_in[5];
  const float* Wk = (const float*)d_in[6];
  const float* Wv = (const float*)d_in[7];
  const float* bv = (const float*)d_in[8];
  const float* Wo = (const float*)d_in[9];
  const float* bo = (const float*)d_in[10];

  float* out  = (float*)d_out;
  float* kout = out + (size_t)MM * DD;
  float* vout = out + 2 * (size_t)MM * DD;

  // ws layout (bytes): wqkv_t 0 | wo_t 9,830,400 | xf16/wv 13,107,200 |
  // qbuf 34,078,720 | vt16 55,050,240 | kt16 76,021,760 -> 96,993,280 total
  char* ws = (char*)d_ws;
  f16* wqkv_t = (f16*)(ws);
  f16* wo_t   = (f16*)(ws + 9830400);
  f16* xf16   = (f16*)(ws + 13107200);
  f16* wvbuf  = (f16*)(ws + 13107200);
  f16* qbuf   = (f16*)(ws + 34078720);
  f16* vt16   = (f16*)(ws + 55050240);
  f16* kt16   = (f16*)(ws + 76021760);
  int use_f16 = (ws_size >= (size_t)96993280) ? 1 : 0;

  prep<<<dim3(11520), 256, 0, stream>>>(Wq, Wk, Wv, Wo, x, wqkv_t, wo_t, xf16);

  gemm_qkv<<<dim3(1920), 256, 0, stream>>>(xf16, wqkv_t, bq, bv, qbuf, kout, vout, kt16, vt16, use_f16);
  attn<<<dim3(1280), 256, 0, stream>>>(qbuf, kt16, vt16, kout, vout, wvbuf, use_f16);
  gemm_out<<<dim3(640), 256, 0, stream>>>(wvbuf, wo_t, bo, out);
}